// Round 1
// baseline (50.229 us; speedup 1.0000x reference)
//
#include <hip/hip_runtime.h>
#include <math.h>

namespace {
constexpr int B = 8, C = 20, H = 512, W = 512;
constexpr float TH0 = 3.0f, TH = 5.0f;
constexpr int GROUPS = B * H * W / 4;   // 4 pixels per thread

__device__ constexpr float SX[9] = {-1, 0, 1, -2, 0, 2, -1, 0, 1};
__device__ constexpr float SY[9] = {-1, -2, -1, 0, 0, 0, 1, 2, 1};
}

__global__ void bl_zero_kernel(float* out) {
    if (threadIdx.x == 0) out[0] = 0.0f;
}

__global__ __launch_bounds__(256) void bl_kernel(const float* __restrict__ logits,
                                                 const int* __restrict__ targets,
                                                 float* __restrict__ out) {
    const int g = blockIdx.x * 256 + threadIdx.x;     // group id, 0..GROUPS-1
    const int w4 = (g & (W / 4 - 1)) * 4;             // base w (multiple of 4)
    const int hh = (g / (W / 4)) & (H - 1);
    const int b  = g / (W / 4 * H);

    // ---- 3x6 clamped target neighborhood (rows hh-1..hh+1, cols w4-1..w4+4)
    int tr[3][6];
    const int tbase = b * H * W;
    #pragma unroll
    for (int i = 0; i < 3; ++i) {
        int hy = hh + i - 1;
        hy = hy < 0 ? 0 : (hy >= H ? H - 1 : hy);
        const int* rp = targets + tbase + hy * W;
        #pragma unroll
        for (int j = 0; j < 6; ++j) {
            int wx = w4 + j - 1;
            wx = wx < 0 ? 0 : (wx >= W ? W - 1 : wx);
            tr[i][j] = rp[wx];
        }
    }

    // ---- 20 classes x 4 pixels of logits, float4 loads, held in registers
    float lv[C][4];
    const float* lp = logits + (size_t)b * C * H * W + (size_t)hh * W + w4;
    #pragma unroll
    for (int c = 0; c < C; ++c) {
        const float4 v = *reinterpret_cast<const float4*>(lp + (size_t)c * (H * W));
        lv[c][0] = v.x; lv[c][1] = v.y; lv[c][2] = v.z; lv[c][3] = v.w;
    }

    float acc = 0.0f;
    #pragma unroll
    for (int p = 0; p < 4; ++p) {
        // ---- log-softmax NLL at target class (all indices compile-time)
        const int tc = tr[1][p + 1];
        float m = lv[0][p];
        #pragma unroll
        for (int c = 1; c < C; ++c) m = fmaxf(m, lv[c][p]);
        float s = 0.0f, lt = 0.0f;
        #pragma unroll
        for (int c = 0; c < C; ++c) {
            s += __expf(lv[c][p] - m);
            lt = (c == tc) ? lv[c][p] : lt;   // cndmask select, no runtime indexing
        }
        const float nll = m + __logf(s) - lt;

        // ---- boundary: max over candidate classes (the 9 window labels) of
        //      Sobel gradient magnitude of the class indicator
        float best = 0.0f;
        #pragma unroll
        for (int k = 0; k < 9; ++k) {
            const int cc = tr[k / 3][p + k % 3];
            float gx = 0.0f, gy = 0.0f;
            #pragma unroll
            for (int q = 0; q < 9; ++q) {
                if (q == 4) continue;  // both Sobel weights zero at center
                const float mt = (tr[q / 3][p + q % 3] == cc) ? 1.0f : 0.0f;
                gx = fmaf(mt, SX[q], gx);
                gy = fmaf(mt, SY[q], gy);
            }
            best = fmaxf(best, fmaf(gx, gx, gy * gy));
        }
        const float wgt = __expf(fminf(TH0 * __fsqrt_rn(best), TH));
        acc = fmaf(nll, wgt, acc);
    }

    // ---- block reduction: wave shuffle -> LDS -> one atomic per block
    #pragma unroll
    for (int off = 32; off > 0; off >>= 1) acc += __shfl_down(acc, off, 64);
    __shared__ float red[4];
    const int lane = threadIdx.x & 63;
    const int wv = threadIdx.x >> 6;
    if (lane == 0) red[wv] = acc;
    __syncthreads();
    if (threadIdx.x == 0) {
        const float tot = red[0] + red[1] + red[2] + red[3];
        atomicAdd(out, tot * (1.0f / (float)(B * H * W)));
    }
}

extern "C" void kernel_launch(void* const* d_in, const int* in_sizes, int n_in,
                              void* d_out, int out_size, void* d_ws, size_t ws_size,
                              hipStream_t stream) {
    const float* logits = (const float*)d_in[0];
    const int* targets = (const int*)d_in[1];
    float* out = (float*)d_out;

    bl_zero_kernel<<<1, 64, 0, stream>>>(out);
    bl_kernel<<<GROUPS / 256, 256, 0, stream>>>(logits, targets, out);
}

// Round 3
// 36.695 us; speedup vs baseline: 1.3688x; 1.3688x over previous
//
#include <hip/hip_runtime.h>
#include <math.h>

namespace {
constexpr int B = 8, C = 20, H = 512, W = 512;
constexpr int HW = H * W;
constexpr int GROUPS = B * H * W / 4;   // 4 pixels per thread
constexpr int NBLK = GROUPS / 256;      // 2048 workgroups
constexpr float INV_N = 1.0f / (float)(B * H * W);

typedef float f32x4 __attribute__((ext_vector_type(4)));

__device__ constexpr float SX[9] = {-1, 0, 1, -2, 0, 2, -1, 0, 1};
__device__ constexpr float SY[9] = {-1, -2, -1, 0, 0, 0, 1, 2, 1};

// weight = exp(min(3*sqrt(best),5)); best = gx^2+gy^2 with integer gx,gy
// -> best in {0,1,2} or >=3  ->  {1, e^3, e^{3*sqrt2}, e^5} exactly.
constexpr float W0 = 1.0f;
constexpr float W1 = 20.085536923187668f;   // e^3
constexpr float W2 = 69.591390994170540f;   // e^{3*sqrt(2)}
constexpr float W3 = 148.41315910257660f;   // e^5
}

__global__ void bl_zero_kernel(float* out) {
    if (threadIdx.x == 0) out[0] = 0.0f;
}

template <bool ATOMIC>
__global__ __launch_bounds__(256) void bl_main(const float* __restrict__ logits,
                                               const int* __restrict__ targets,
                                               float* __restrict__ outp) {
    const int g = blockIdx.x * 256 + threadIdx.x;     // group id
    const int w4 = (g & (W / 4 - 1)) * 4;             // base w (multiple of 4)
    const int hh = (g >> 7) & (H - 1);                // W/4 == 128
    const int b  = g >> 16;                           // 128*512 == 65536

    // ---- phase 1: targets window -> per-pixel weight + target class -------
    int tr[3][6];
    const int tbase = b * H * W;
    #pragma unroll
    for (int i = 0; i < 3; ++i) {
        int hy = hh + i - 1;
        hy = hy < 0 ? 0 : (hy >= H ? H - 1 : hy);
        const int* rp = targets + tbase + hy * W;
        #pragma unroll
        for (int j = 0; j < 6; ++j) {
            int wx = w4 + j - 1;
            wx = wx < 0 ? 0 : (wx >= W ? W - 1 : wx);
            tr[i][j] = rp[wx];
        }
    }

    float wgt[4];
    int tc[4];
    #pragma unroll
    for (int p = 0; p < 4; ++p) {
        tc[p] = tr[1][p + 1];
        float best = 0.0f;
        #pragma unroll
        for (int k = 0; k < 9; ++k) {
            const int cc = tr[k / 3][p + k % 3];
            float gx = 0.0f, gy = 0.0f;
            #pragma unroll
            for (int q = 0; q < 9; ++q) {
                if (q == 4) continue;  // both Sobel weights zero at center
                const float mt = (tr[q / 3][p + q % 3] == cc) ? 1.0f : 0.0f;
                gx = fmaf(mt, SX[q], gx);
                gy = fmaf(mt, SY[q], gy);
            }
            best = fmaxf(best, fmaf(gx, gx, gy * gy));
        }
        wgt[p] = best > 2.5f ? W3 : (best > 1.5f ? W2 : (best > 0.5f ? W1 : W0));
    }

    // ---- phase 2: streaming max-free softmax over 2 halves of 10 classes --
    float s[4]  = {0.0f, 0.0f, 0.0f, 0.0f};
    float lt[4] = {0.0f, 0.0f, 0.0f, 0.0f};
    const float* lp = logits + (size_t)b * C * HW + (size_t)hh * W + w4;

    #pragma unroll 1
    for (int half = 0; half < 2; ++half) {
        f32x4 v[10];
        const float* hp = lp + (size_t)half * 10 * HW;
        #pragma unroll
        for (int i = 0; i < 10; ++i)
            v[i] = __builtin_nontemporal_load(
                reinterpret_cast<const f32x4*>(hp + (size_t)i * HW));
        const int cbase = half * 10;
        #pragma unroll
        for (int i = 0; i < 10; ++i) {
            s[0] += __expf(v[i].x);
            s[1] += __expf(v[i].y);
            s[2] += __expf(v[i].z);
            s[3] += __expf(v[i].w);
            const int c = cbase + i;
            lt[0] = (c == tc[0]) ? v[i].x : lt[0];
            lt[1] = (c == tc[1]) ? v[i].y : lt[1];
            lt[2] = (c == tc[2]) ? v[i].z : lt[2];
            lt[3] = (c == tc[3]) ? v[i].w : lt[3];
        }
    }

    float acc = 0.0f;
    #pragma unroll
    for (int p = 0; p < 4; ++p)
        acc = fmaf(__logf(s[p]) - lt[p], wgt[p], acc);

    // ---- block reduction ---------------------------------------------------
    #pragma unroll
    for (int off = 32; off > 0; off >>= 1) acc += __shfl_down(acc, off, 64);
    __shared__ float red[4];
    const int lane = threadIdx.x & 63;
    const int wv = threadIdx.x >> 6;
    if (lane == 0) red[wv] = acc;
    __syncthreads();
    if (threadIdx.x == 0) {
        const float tot = red[0] + red[1] + red[2] + red[3];
        if (ATOMIC) atomicAdd(outp, tot * INV_N);
        else        outp[blockIdx.x] = tot;
    }
}

__global__ __launch_bounds__(256) void bl_reduce(const float* __restrict__ partials,
                                                 float* __restrict__ out) {
    float a = 0.0f;
    #pragma unroll
    for (int i = 0; i < NBLK / 256; ++i)
        a += partials[i * 256 + threadIdx.x];
    #pragma unroll
    for (int off = 32; off > 0; off >>= 1) a += __shfl_down(a, off, 64);
    __shared__ float red[4];
    const int lane = threadIdx.x & 63;
    const int wv = threadIdx.x >> 6;
    if (lane == 0) red[wv] = a;
    __syncthreads();
    if (threadIdx.x == 0)
        out[0] = (red[0] + red[1] + red[2] + red[3]) * INV_N;
}

extern "C" void kernel_launch(void* const* d_in, const int* in_sizes, int n_in,
                              void* d_out, int out_size, void* d_ws, size_t ws_size,
                              hipStream_t stream) {
    const float* logits = (const float*)d_in[0];
    const int* targets = (const int*)d_in[1];
    float* out = (float*)d_out;

    if (ws_size >= (size_t)NBLK * sizeof(float)) {
        float* partials = (float*)d_ws;
        bl_main<false><<<NBLK, 256, 0, stream>>>(logits, targets, partials);
        bl_reduce<<<1, 256, 0, stream>>>(partials, out);
    } else {
        bl_zero_kernel<<<1, 64, 0, stream>>>(out);
        bl_main<true><<<NBLK, 256, 0, stream>>>(logits, targets, out);
    }
}

// Round 4
// 33.527 us; speedup vs baseline: 1.4981x; 1.0945x over previous
//
#include <hip/hip_runtime.h>
#include <math.h>

namespace {
constexpr int B = 8, C = 20, H = 512, W = 512;
constexpr int HW = H * W;
constexpr int GROUPS = B * H * W / 4;   // 4 pixels per thread
constexpr int NBLK = GROUPS / 256;      // 2048 workgroups
constexpr float INV_N = 1.0f / (float)(B * H * W);

typedef float f32x4 __attribute__((ext_vector_type(4)));

// weight = exp(min(3*sqrt(best),5)); best = gx^2+gy^2 with integer gx,gy
// -> best in {0,1,2} or >=3  ->  {1, e^3, e^{3*sqrt2}, e^5} exactly.
constexpr float W0 = 1.0f;
constexpr float W1 = 20.085536923187668f;   // e^3
constexpr float W2 = 69.591390994170540f;   // e^{3*sqrt(2)}
constexpr float W3 = 148.41315910257660f;   // e^5
}

__global__ void bl_zero_kernel(float* out) {
    if (threadIdx.x == 0) out[0] = 0.0f;
}

template <bool ATOMIC>
__global__ __launch_bounds__(256) void bl_main(const float* __restrict__ logits,
                                               const int* __restrict__ targets,
                                               float* __restrict__ outp) {
    const int g = blockIdx.x * 256 + threadIdx.x;     // group id
    const int w4 = (g & (W / 4 - 1)) * 4;             // base w (multiple of 4)
    const int hh = (g >> 7) & (H - 1);                // W/4 == 128
    const int b  = g >> 16;                           // 128*512 == 65536

    // ---- issue target-window loads: per row one aligned int4 + 2 edge ints
    const int* tb = targets + b * H * W;
    const int wl = w4 - 1 < 0 ? 0 : w4 - 1;
    const int wr = w4 + 4 > W - 1 ? W - 1 : w4 + 4;
    int tr[3][6];
    #pragma unroll
    for (int i = 0; i < 3; ++i) {
        int hy = hh + i - 1;
        hy = hy < 0 ? 0 : (hy >= H ? H - 1 : hy);
        const int* rp = tb + hy * W;
        const int4 mid = *reinterpret_cast<const int4*>(rp + w4);  // 16B aligned
        tr[i][0] = rp[wl];
        tr[i][1] = mid.x; tr[i][2] = mid.y; tr[i][3] = mid.z; tr[i][4] = mid.w;
        tr[i][5] = rp[wr];
    }

    // ---- issue half-0 logit loads (10 x float4) so they fly during boundary
    const float* lp = logits + (size_t)b * C * HW + (size_t)hh * W + w4;
    f32x4 v0[10];
    #pragma unroll
    for (int i = 0; i < 10; ++i)
        v0[i] = __builtin_nontemporal_load(
            reinterpret_cast<const f32x4*>(lp + (size_t)i * HW));

    // ---- boundary weight per pixel (center candidate has zero Sobel weight:
    //      max over the 8 neighbor labels == max over all classes)
    float wgt[4];
    int tc[4];
    #pragma unroll
    for (int p = 0; p < 4; ++p) {
        tc[p] = tr[1][p + 1];
        float best = 0.0f;
        #pragma unroll
        for (int k = 0; k < 9; ++k) {
            if (k == 4) continue;
            const int cc = tr[k / 3][p + k % 3];
            const float e0 = (tr[0][p + 0] == cc) ? 1.0f : 0.0f;
            const float e1 = (tr[0][p + 1] == cc) ? 1.0f : 0.0f;
            const float e2 = (tr[0][p + 2] == cc) ? 1.0f : 0.0f;
            const float e3 = (tr[1][p + 0] == cc) ? 1.0f : 0.0f;
            const float e5 = (tr[1][p + 2] == cc) ? 1.0f : 0.0f;
            const float e6 = (tr[2][p + 0] == cc) ? 1.0f : 0.0f;
            const float e7 = (tr[2][p + 1] == cc) ? 1.0f : 0.0f;
            const float e8 = (tr[2][p + 2] == cc) ? 1.0f : 0.0f;
            const float gx = (fmaf(2.0f, e5, e2) + e8) - (fmaf(2.0f, e3, e0) + e6);
            const float gy = (fmaf(2.0f, e7, e6) + e8) - (fmaf(2.0f, e1, e0) + e2);
            best = fmaxf(best, fmaf(gx, gx, gy * gy));
        }
        wgt[p] = best > 2.5f ? W3 : (best > 1.5f ? W2 : (best > 0.5f ? W1 : W0));
    }

    // ---- issue half-1 loads, then consume half-0 (covers half-1 latency) --
    f32x4 v1[10];
    #pragma unroll
    for (int i = 0; i < 10; ++i)
        v1[i] = __builtin_nontemporal_load(
            reinterpret_cast<const f32x4*>(lp + (size_t)(10 + i) * HW));

    float s[4]  = {0.0f, 0.0f, 0.0f, 0.0f};
    float lt[4] = {0.0f, 0.0f, 0.0f, 0.0f};
    #pragma unroll
    for (int i = 0; i < 10; ++i) {
        s[0] += __expf(v0[i].x);
        s[1] += __expf(v0[i].y);
        s[2] += __expf(v0[i].z);
        s[3] += __expf(v0[i].w);
        lt[0] = (i == tc[0]) ? v0[i].x : lt[0];
        lt[1] = (i == tc[1]) ? v0[i].y : lt[1];
        lt[2] = (i == tc[2]) ? v0[i].z : lt[2];
        lt[3] = (i == tc[3]) ? v0[i].w : lt[3];
    }
    #pragma unroll
    for (int i = 0; i < 10; ++i) {
        const int c = 10 + i;
        s[0] += __expf(v1[i].x);
        s[1] += __expf(v1[i].y);
        s[2] += __expf(v1[i].z);
        s[3] += __expf(v1[i].w);
        lt[0] = (c == tc[0]) ? v1[i].x : lt[0];
        lt[1] = (c == tc[1]) ? v1[i].y : lt[1];
        lt[2] = (c == tc[2]) ? v1[i].z : lt[2];
        lt[3] = (c == tc[3]) ? v1[i].w : lt[3];
    }

    float acc = 0.0f;
    #pragma unroll
    for (int p = 0; p < 4; ++p)
        acc = fmaf(__logf(s[p]) - lt[p], wgt[p], acc);

    // ---- block reduction ---------------------------------------------------
    #pragma unroll
    for (int off = 32; off > 0; off >>= 1) acc += __shfl_down(acc, off, 64);
    __shared__ float red[4];
    const int lane = threadIdx.x & 63;
    const int wv = threadIdx.x >> 6;
    if (lane == 0) red[wv] = acc;
    __syncthreads();
    if (threadIdx.x == 0) {
        const float tot = red[0] + red[1] + red[2] + red[3];
        if (ATOMIC) atomicAdd(outp, tot * INV_N);
        else        outp[blockIdx.x] = tot;
    }
}

__global__ __launch_bounds__(256) void bl_reduce(const float* __restrict__ partials,
                                                 float* __restrict__ out) {
    float a = 0.0f;
    #pragma unroll
    for (int i = 0; i < NBLK / 256; ++i)
        a += partials[i * 256 + threadIdx.x];
    #pragma unroll
    for (int off = 32; off > 0; off >>= 1) a += __shfl_down(a, off, 64);
    __shared__ float red[4];
    const int lane = threadIdx.x & 63;
    const int wv = threadIdx.x >> 6;
    if (lane == 0) red[wv] = a;
    __syncthreads();
    if (threadIdx.x == 0)
        out[0] = (red[0] + red[1] + red[2] + red[3]) * INV_N;
}

extern "C" void kernel_launch(void* const* d_in, const int* in_sizes, int n_in,
                              void* d_out, int out_size, void* d_ws, size_t ws_size,
                              hipStream_t stream) {
    const float* logits = (const float*)d_in[0];
    const int* targets = (const int*)d_in[1];
    float* out = (float*)d_out;

    if (ws_size >= (size_t)NBLK * sizeof(float)) {
        float* partials = (float*)d_ws;
        bl_main<false><<<NBLK, 256, 0, stream>>>(logits, targets, partials);
        bl_reduce<<<1, 256, 0, stream>>>(partials, out);
    } else {
        bl_zero_kernel<<<1, 64, 0, stream>>>(out);
        bl_main<true><<<NBLK, 256, 0, stream>>>(logits, targets, out);
    }
}